// Round 11
// baseline (263.500 us; speedup 1.0000x reference)
//
#include <hip/hip_runtime.h>
#include <hip/hip_bf16.h>
#include <math.h>

#define B_ 2
#define H_ 8
#define N_ 2048
#define D_ 64
#define BH_ 16
#define NT_ (N_/64)
#define LS 72
#define LSW (LS/2)

typedef __attribute__((ext_vector_type(8))) short short8;
typedef __attribute__((ext_vector_type(4))) float float4v;

__device__ __forceinline__ unsigned packbf2(float a, float b){
  __hip_bfloat162 h = __float22bfloat162_rn(make_float2(a, b));
  return *(unsigned*)&h;
}
__device__ __forceinline__ void split2(float a, float b, unsigned& hi, unsigned& lo){
  hi = packbf2(a, b);
  float ha = __uint_as_float(hi << 16);
  float hb = __uint_as_float(hi & 0xFFFF0000u);
  lo = packbf2(a - ha, b - hb);
}
__device__ __forceinline__ void load_split8(const float* p, short8& hi8, short8& lo8){
  float4v v0 = *(const float4v*)p;
  float4v v1 = *(const float4v*)(p + 4);
  unsigned h0,h1,h2,h3,l0,l1,l2,l3;
  split2(v0.x, v0.y, h0, l0);
  split2(v0.z, v0.w, h1, l1);
  split2(v1.x, v1.y, h2, l2);
  split2(v1.z, v1.w, h3, l3);
  unsigned ph[4] = {h0,h1,h2,h3};
  unsigned pl[4] = {l0,l1,l2,l3};
  hi8 = *(short8*)ph;
  lo8 = *(short8*)pl;
}

// score = (1 + acos(clip(qk)))^(-5), masked -> (1+10000)^-5.
// acos via A&S 4.4.45 (|err| < ~7e-5 rad).
__device__ __forceinline__ float score_fn(float qk, float masked){
  float ax = fminf(fabsf(qk), 1.0f - 1e-7f);
  float t  = __builtin_amdgcn_sqrtf(1.0f - ax);
  float p  = __builtin_fmaf(__builtin_fmaf(__builtin_fmaf(-0.0187293f, ax, 0.0742610f),
                                           ax, -0.2121144f), ax, 1.5707288f);
  float t2 = t * p;
  float g  = (qk >= 0.0f) ? t2 : (3.14159265358979f - t2);
  g = (masked != 0.0f) ? 10000.0f : g;
  float w1 = 1.0f + g;
  float w2 = w1*w1;
  float w4 = w2*w2;
  float w5 = w4*w1;
  return __builtin_amdgcn_rcpf(w5);
}

// k1 (STORE=true): scores -> S bf16 (tile-blocked [bh][kt][row][64key]),
// col sums atomically into ncw. (STORE=false): fallback pass1, ncw=n_c^-0.5.
// Barrier-free main loop: K fragments in registers, Q fragments direct global.
template<bool STORE>
__global__ __launch_bounds__(256) void k1_score(
    const float* __restrict__ Q, const float* __restrict__ K,
    const int* __restrict__ mask, float* __restrict__ ncw,
    unsigned short* __restrict__ S)
{
  __shared__ float msk[64];
  __shared__ float red[64*4];

  const int kt = blockIdx.x, bh = blockIdx.y, rz = blockIdx.z;
  const int nz = gridDim.z;
  const int tid = threadIdx.x;
  const int wv = tid>>6, lane = tid&63, quad = lane>>4, l15 = lane&15;

  const float* Qg = Q + (size_t)bh*N_*D_;
  const float* Kg = K + (size_t)bh*N_*D_;

  short8 khi[4][2], klo[4][2];
  #pragma unroll
  for (int s=0;s<4;++s){
    const float* kp = Kg + (size_t)(kt*64 + s*16 + l15)*D_ + quad*8;
    load_split8(kp,      khi[s][0], klo[s][0]);
    load_split8(kp + 32, khi[s][1], klo[s][1]);
  }
  if (tid < 64)
    msk[tid] = (mask[(bh>>3)*N_ + kt*64 + tid] == 0) ? 1.f : 0.f;
  __syncthreads();

  float cs[4][4];
  #pragma unroll
  for (int s=0;s<4;++s)
    #pragma unroll
    for (int i=0;i<4;++i) cs[s][i] = 0.f;

  const int iters = NT_/nz;
  for (int rti=0; rti<iters; ++rti){
    const int rt = rz*iters + rti;
    const float* qp = Qg + (size_t)(rt*64 + wv*16 + l15)*D_ + quad*8;
    short8 bhi[2], blo[2];
    load_split8(qp,      bhi[0], blo[0]);
    load_split8(qp + 32, bhi[1], blo[1]);

    const size_t nrow = (size_t)(bh*NT_ + kt)*N_ + (size_t)rt*64 + wv*16 + l15;
    #pragma unroll
    for (int s=0;s<4;++s){
      float4v c = {0.f,0.f,0.f,0.f};
      #pragma unroll
      for (int cc=0; cc<2; ++cc){
        c = __builtin_amdgcn_mfma_f32_16x16x32_bf16(khi[s][cc], bhi[cc], c, 0,0,0);
        c = __builtin_amdgcn_mfma_f32_16x16x32_bf16(khi[s][cc], blo[cc], c, 0,0,0);
        c = __builtin_amdgcn_mfma_f32_16x16x32_bf16(klo[s][cc], bhi[cc], c, 0,0,0);
      }
      int kl = s*16 + quad*4;
      float sc0 = score_fn(c[0], msk[kl+0]);
      float sc1 = score_fn(c[1], msk[kl+1]);
      float sc2 = score_fn(c[2], msk[kl+2]);
      float sc3 = score_fn(c[3], msk[kl+3]);
      cs[s][0]+=sc0; cs[s][1]+=sc1; cs[s][2]+=sc2; cs[s][3]+=sc3;
      if (STORE){
        uint2 pk;
        pk.x = packbf2(sc0, sc1);
        pk.y = packbf2(sc2, sc3);
        *(uint2*)&S[nrow*64 + kl] = pk;
      }
    }
  }

  #pragma unroll
  for (int s=0;s<4;++s)
    #pragma unroll
    for (int i=0;i<4;++i){
      float v2 = cs[s][i];
      v2 += __shfl_xor(v2, 1);
      v2 += __shfl_xor(v2, 2);
      v2 += __shfl_xor(v2, 4);
      v2 += __shfl_xor(v2, 8);
      cs[s][i] = v2;
    }
  if (l15 == 0){
    #pragma unroll
    for (int s=0;s<4;++s)
      #pragma unroll
      for (int i=0;i<4;++i)
        red[(s*16 + quad*4 + i)*4 + wv] = cs[s][i];
  }
  __syncthreads();
  if (tid < 64){
    float t = red[tid*4+0] + red[tid*4+1] + red[tid*4+2] + red[tid*4+3];
    if (STORE) atomicAdd(&ncw[bh*N_ + kt*64 + tid], t);
    else       ncw[bh*N_ + kt*64 + tid] = 1.0f / sqrtf(t);
  }
}

// k2_pack: Vw in MFMA-fragment order: [bh][kt][f=0..9][lane][8 bf16]
//   f = s2*2+cc, s2<4: element j = w[key]*V[key][d], d=s2*16+l15,
//                       key = kt*64 + cc*32 + quad*8 + j
//   f = 8,9 (cc=f&1): l15==0 -> w[key], else 0   (rowsum operand row)
__global__ __launch_bounds__(256) void k2_pack(
    const float* __restrict__ V, const float* __restrict__ nc,
    unsigned short* __restrict__ Vw)
{
  __shared__ float T[64*65];    // T[d][m] = w*V^T for this tile
  __shared__ float wrow[64];
  const int mt = blockIdx.x, bh = blockIdx.y;
  const int tid = threadIdx.x;
  const float* Vg = V + (size_t)bh*N_*D_;
  const float* ncg = nc + (size_t)bh*N_;
  unsigned short* Fb = Vw + ((size_t)(bh*NT_ + mt)*10)*512;

  {
    int m = tid >> 2;
    int d0 = (tid & 3) * 16;
    int gm = mt*64 + m;
    float wm = 1.0f / sqrtf(fmaxf(ncg[gm], 1e-30f));
    if (d0 == 0) wrow[m] = wm;
    #pragma unroll
    for (int j=0;j<4;++j){
      float4v v = *(const float4v*)(Vg + (size_t)gm*D_ + d0 + j*4);
      T[(d0+j*4+0)*65 + m] = v.x*wm;
      T[(d0+j*4+1)*65 + m] = v.y*wm;
      T[(d0+j*4+2)*65 + m] = v.z*wm;
      T[(d0+j*4+3)*65 + m] = v.w*wm;
    }
  }
  __syncthreads();

  for (int idx = tid; idx < 640; idx += 256){
    int f = idx >> 6, lane = idx & 63;
    int quad = lane >> 4, l15 = lane & 15;
    int s2 = f >> 1, cc = f & 1;
    int m0 = cc*32 + quad*8;
    unsigned pk[4];
    if (s2 < 4){
      int d = s2*16 + l15;
      #pragma unroll
      for (int j=0;j<4;++j)
        pk[j] = packbf2(T[d*65 + m0 + 2*j], T[d*65 + m0 + 2*j + 1]);
    } else if (l15 == 0){
      #pragma unroll
      for (int j=0;j<4;++j)
        pk[j] = packbf2(wrow[m0 + 2*j], wrow[m0 + 2*j + 1]);
    } else {
      pk[0]=pk[1]=pk[2]=pk[3]=0u;
    }
    *(short8*)(Fb + ((size_t)f*64 + lane)*8) = *(short8*)pk;
  }
}

// k3_stream v3: out = (S diag(w) V) / (S w).
// 16 waves: sr2 = wave&1 (two 16-row subtiles), kc = wave>>1 (8 chunks x 4 kt).
// Per kt: 4 S loads + 10 Vw loads -> 20 MFMAs (two row-sets share Vw frags).
// Final reduce: LDS float atomicAdd into Racc[64][67], then normalize+store.
__global__ __launch_bounds__(1024) void k3_stream(
    const unsigned short* __restrict__ S, const unsigned short* __restrict__ Vw,
    float* __restrict__ out)
{
  __shared__ float Racc[64*67];   // per row: [0..63]=O, [64]=rowsum; stride 67

  const int rt = blockIdx.x, bh = blockIdx.y;
  const int tid = threadIdx.x;
  const int wvid = tid >> 6;          // 0..15
  const int sr2 = wvid & 1;           // row half
  const int kc  = wvid >> 1;          // 0..7, 4 key tiles each
  const int lane = tid & 63, quad = lane>>4, l15 = lane&15;

  for (int z = tid; z < 64*67; z += 1024) Racc[z] = 0.f;

  float4v accA[4], accB[4];
  #pragma unroll
  for (int i=0;i<4;++i){ accA[i] = (float4v){0.f,0.f,0.f,0.f}; accB[i] = (float4v){0.f,0.f,0.f,0.f}; }
  float4v c5A = {0.f,0.f,0.f,0.f}, c5B = {0.f,0.f,0.f,0.f};

  const size_t srowA = (size_t)rt*64 + sr2*32 + l15;   // global row, set A
  const size_t srowB = srowA + 16;                     // set B

  short8 nA0, nA1, nB0, nB1;
  {
    const size_t ba = ((size_t)(bh*NT_ + kc*4)*N_ + srowA)*64;
    const size_t bb = ((size_t)(bh*NT_ + kc*4)*N_ + srowB)*64;
    nA0 = *(const short8*)&S[ba +  0 + quad*8];
    nA1 = *(const short8*)&S[ba + 32 + quad*8];
    nB0 = *(const short8*)&S[bb +  0 + quad*8];
    nB1 = *(const short8*)&S[bb + 32 + quad*8];
  }

  __syncthreads();   // Racc zeroed before any atomic adds

  for (int ki=0; ki<4; ++ki){
    const int kt = kc*4 + ki;
    short8 pA0 = nA0, pA1 = nA1, pB0 = nB0, pB1 = nB1;
    {
      const int ktn = kc*4 + (ki < 3 ? ki+1 : 3);
      const size_t ba = ((size_t)(bh*NT_ + ktn)*N_ + srowA)*64;
      const size_t bb = ((size_t)(bh*NT_ + ktn)*N_ + srowB)*64;
      nA0 = *(const short8*)&S[ba +  0 + quad*8];
      nA1 = *(const short8*)&S[ba + 32 + quad*8];
      nB0 = *(const short8*)&S[bb +  0 + quad*8];
      nB1 = *(const short8*)&S[bb + 32 + quad*8];
    }
    const unsigned short* F = Vw + ((size_t)(bh*NT_ + kt)*10)*512 + (size_t)lane*8;
    #pragma unroll
    for (int s2=0;s2<4;++s2){
      const short8 a0 = *(const short8*)(F + (size_t)(s2*2+0)*512);
      const short8 a1 = *(const short8*)(F + (size_t)(s2*2+1)*512);
      accA[s2] = __builtin_amdgcn_mfma_f32_16x16x32_bf16(a0, pA0, accA[s2], 0,0,0);
      accA[s2] = __builtin_amdgcn_mfma_f32_16x16x32_bf16(a1, pA1, accA[s2], 0,0,0);
      accB[s2] = __builtin_amdgcn_mfma_f32_16x16x32_bf16(a0, pB0, accB[s2], 0,0,0);
      accB[s2] = __builtin_amdgcn_mfma_f32_16x16x32_bf16(a1, pB1, accB[s2], 0,0,0);
    }
    {
      const short8 a8 = *(const short8*)(F + (size_t)8*512);
      const short8 a9 = *(const short8*)(F + (size_t)9*512);
      c5A = __builtin_amdgcn_mfma_f32_16x16x32_bf16(a8, pA0, c5A, 0,0,0);
      c5A = __builtin_amdgcn_mfma_f32_16x16x32_bf16(a9, pA1, c5A, 0,0,0);
      c5B = __builtin_amdgcn_mfma_f32_16x16x32_bf16(a8, pB0, c5B, 0,0,0);
      c5B = __builtin_amdgcn_mfma_f32_16x16x32_bf16(a9, pB1, c5B, 0,0,0);
    }
  }

  // accumulate partials into Racc (8 kc chunks add per row)
  {
    const int rowA = sr2*32 + l15;
    const int rowB = rowA + 16;
    #pragma unroll
    for (int s2=0;s2<4;++s2)
      #pragma unroll
      for (int i=0;i<4;++i){
        atomicAdd(&Racc[rowA*67 + s2*16 + quad*4 + i], accA[s2][i]);
        atomicAdd(&Racc[rowB*67 + s2*16 + quad*4 + i], accB[s2][i]);
      }
    if (quad == 0){
      atomicAdd(&Racc[rowA*67 + 64], c5A[0]);
      atomicAdd(&Racc[rowB*67 + 64], c5B[0]);
    }
  }
  __syncthreads();

  // normalize + store: thread -> (row, 4 cols)
  {
    const int row = tid >> 4;
    const int c4  = (tid & 15) * 4;
    const float inv = 1.0f / fmaxf(Racc[row*67 + 64], 1e-12f);
    float4v o;
    o.x = Racc[row*67 + c4 + 0] * inv;
    o.y = Racc[row*67 + c4 + 1] * inv;
    o.z = Racc[row*67 + c4 + 2] * inv;
    o.w = Racc[row*67 + c4 + 3] * inv;
    *(float4v*)(out + (size_t)bh*N_*D_ + (size_t)(rt*64 + row)*D_ + c4) = o;
  }
}

// fallback pass2 (round-3 structure, verified)
__global__ __launch_bounds__(256) void spop_pass2(
    const float* __restrict__ Q, const float* __restrict__ K,
    const float* __restrict__ V, const int* __restrict__ mask,
    const float* __restrict__ w, float* __restrict__ out)
{
  __shared__ unsigned short Khi[64*LS], Klo[64*LS];
  __shared__ unsigned short Vt[64*LS];
  __shared__ unsigned short Ps[64*LS];
  __shared__ float msk[64], wms[64];

  const int rt = blockIdx.x, bh = blockIdx.y, b = bh>>3;
  const int tid = threadIdx.x;
  const int wv = tid>>6, lane = tid&63, quad = lane>>4, l15 = lane&15;

  const float* Qg = Q + (size_t)bh*N_*D_;
  const float* Kg = K + (size_t)bh*N_*D_;
  const float* Vg = V + (size_t)bh*N_*D_;

  short8 qhi[2], qlo[2];
  {
    const float* qp = Qg + (size_t)(rt*64 + wv*16 + l15)*D_ + quad*8;
    load_split8(qp,      qhi[0], qlo[0]);
    load_split8(qp + 32, qhi[1], qlo[1]);
  }

  float4v acc[4];
  #pragma unroll
  for (int i=0;i<4;++i) acc[i] = (float4v){0.f,0.f,0.f,0.f};
  float rs = 0.f;

  for (int kt=0; kt<NT_; ++kt){
    __syncthreads();
    #pragma unroll
    for (int it=0; it<4; ++it){
      int idx = tid + it*256;
      int r = idx>>4, d4 = (idx&15)<<2;
      const float4v v = *(const float4v*)(Kg + (size_t)(kt*64 + r)*D_ + d4);
      unsigned h0,l0,h1,l1;
      split2(v.x, v.y, h0, l0);
      split2(v.z, v.w, h1, l1);
      unsigned* KhiW = (unsigned*)Khi; unsigned* KloW = (unsigned*)Klo;
      int base = r*LSW + (d4>>1);
      KhiW[base] = h0; KhiW[base+1] = h1;
      KloW[base] = l0; KloW[base+1] = l1;
    }
    #pragma unroll
    for (int it=0; it<2; ++it){
      int u = tid + it*256;
      int kp = u & 31;
      int d4 = (u>>5)<<2;
      const float* vp = Vg + (size_t)(kt*64 + kp*2)*D_ + d4;
      float4v a0 = *(const float4v*)vp;
      float4v a1 = *(const float4v*)(vp + D_);
      unsigned* VtW = (unsigned*)Vt;
      VtW[(d4+0)*LSW + kp] = packbf2(a0.x, a1.x);
      VtW[(d4+1)*LSW + kp] = packbf2(a0.y, a1.y);
      VtW[(d4+2)*LSW + kp] = packbf2(a0.z, a1.z);
      VtW[(d4+3)*LSW + kp] = packbf2(a0.w, a1.w);
    }
    if (tid < 64){
      int gk = kt*64 + tid;
      msk[tid] = (mask[b*N_ + gk] == 0) ? 1.f : 0.f;
      wms[tid] = w[bh*N_ + gk];
    }
    __syncthreads();

    #pragma unroll
    for (int s=0;s<4;++s){
      float4v c = {0.f,0.f,0.f,0.f};
      #pragma unroll
      for (int cc=0; cc<2; ++cc){
        const short8 ahi = *(const short8*)&Khi[(s*16+l15)*LS + cc*32 + quad*8];
        const short8 alo = *(const short8*)&Klo[(s*16+l15)*LS + cc*32 + quad*8];
        c = __builtin_amdgcn_mfma_f32_16x16x32_bf16(ahi, qhi[cc], c, 0,0,0);
        c = __builtin_amdgcn_mfma_f32_16x16x32_bf16(ahi, qlo[cc], c, 0,0,0);
        c = __builtin_amdgcn_mfma_f32_16x16x32_bf16(alo, qhi[cc], c, 0,0,0);
      }
      int kl = s*16 + quad*4;
      float sc0 = score_fn(c[0], msk[kl+0]) * wms[kl+0];
      float sc1 = score_fn(c[1], msk[kl+1]) * wms[kl+1];
      float sc2 = score_fn(c[2], msk[kl+2]) * wms[kl+2];
      float sc3 = score_fn(c[3], msk[kl+3]) * wms[kl+3];
      rs += (sc0 + sc1) + (sc2 + sc3);
      unsigned* PsW = (unsigned*)Ps;
      int pb = (wv*16 + l15)*LSW + (kl>>1);
      PsW[pb]   = packbf2(sc0, sc1);
      PsW[pb+1] = packbf2(sc2, sc3);
    }

    short8 pf[2];
    pf[0] = *(const short8*)&Ps[(wv*16+l15)*LS +  0 + quad*8];
    pf[1] = *(const short8*)&Ps[(wv*16+l15)*LS + 32 + quad*8];
    #pragma unroll
    for (int s2=0;s2<4;++s2){
      #pragma unroll
      for (int cc=0; cc<2; ++cc){
        const short8 av = *(const short8*)&Vt[(s2*16+l15)*LS + cc*32 + quad*8];
        acc[s2] = __builtin_amdgcn_mfma_f32_16x16x32_bf16(av, pf[cc], acc[s2], 0,0,0);
      }
    }
  }

  rs += __shfl_xor(rs, 16);
  rs += __shfl_xor(rs, 32);
  float inv = 1.0f / fmaxf(rs, 1e-12f);

  float* Og = out + (size_t)bh*N_*D_ + (size_t)(rt*64 + wv*16 + l15)*D_;
  #pragma unroll
  for (int s2=0;s2<4;++s2)
    #pragma unroll
    for (int i=0;i<4;++i)
      Og[s2*16 + quad*4 + i] = acc[s2][i] * inv;
}

extern "C" void kernel_launch(void* const* d_in, const int* in_sizes, int n_in,
                              void* d_out, int out_size, void* d_ws, size_t ws_size,
                              hipStream_t stream) {
  (void)in_sizes; (void)n_in; (void)out_size;
  const float* Q   = (const float*)d_in[0];
  const float* K   = (const float*)d_in[1];
  const float* V   = (const float*)d_in[2];
  const int*  mask = (const int*)d_in[3];
  float* out = (float*)d_out;

  const size_t nc_bytes = (size_t)BH_*N_*sizeof(float);        // 128 KB
  const size_t vw_off   = 131072;
  const size_t vw_bytes = (size_t)BH_*NT_*10*512*2;            // 5.24 MB
  const size_t s_off    = vw_off + vw_bytes;
  const size_t S_bytes  = (size_t)2*BH_*N_*N_;                 // 128 MiB
  const size_t need     = s_off + S_bytes;                     // ~139.6 MB (proven fits)

  if (ws_size >= need){
    float* nc = (float*)d_ws;
    unsigned short* Vw = (unsigned short*)((char*)d_ws + vw_off);
    unsigned short* S  = (unsigned short*)((char*)d_ws + s_off);
    hipMemsetAsync(nc, 0, nc_bytes, stream);
    k1_score<true><<<dim3(NT_, BH_, 4), 256, 0, stream>>>(Q, K, mask, nc, S);
    k2_pack<<<dim3(NT_, BH_), 256, 0, stream>>>(V, nc, Vw);
    k3_stream<<<dim3(NT_, BH_), 1024, 0, stream>>>(S, Vw, out);
  } else {
    float* w = (float*)d_ws;
    k1_score<false><<<dim3(NT_, BH_, 1), 256, 0, stream>>>(Q, K, mask, w, nullptr);
    spop_pass2<<<dim3(NT_, BH_), 256, 0, stream>>>(Q, K, V, mask, w, out);
  }
}

// Round 13
// 193.448 us; speedup vs baseline: 1.3621x; 1.3621x over previous
//
#include <hip/hip_runtime.h>
#include <hip/hip_bf16.h>
#include <math.h>

#define B_ 2
#define H_ 8
#define N_ 2048
#define D_ 64
#define BH_ 16
#define NT_ (N_/64)
#define LS 72
#define LSW (LS/2)

typedef __attribute__((ext_vector_type(8))) short short8;
typedef __attribute__((ext_vector_type(4))) float float4v;

__device__ __forceinline__ unsigned packbf2(float a, float b){
  __hip_bfloat162 h = __float22bfloat162_rn(make_float2(a, b));
  return *(unsigned*)&h;
}
__device__ __forceinline__ void split2(float a, float b, unsigned& hi, unsigned& lo){
  hi = packbf2(a, b);
  float ha = __uint_as_float(hi << 16);
  float hb = __uint_as_float(hi & 0xFFFF0000u);
  lo = packbf2(a - ha, b - hb);
}
__device__ __forceinline__ void load_split8(const float* p, short8& hi8, short8& lo8){
  float4v v0 = *(const float4v*)p;
  float4v v1 = *(const float4v*)(p + 4);
  unsigned h0,h1,h2,h3,l0,l1,l2,l3;
  split2(v0.x, v0.y, h0, l0);
  split2(v0.z, v0.w, h1, l1);
  split2(v1.x, v1.y, h2, l2);
  split2(v1.z, v1.w, h3, l3);
  unsigned ph[4] = {h0,h1,h2,h3};
  unsigned pl[4] = {l0,l1,l2,l3};
  hi8 = *(short8*)ph;
  lo8 = *(short8*)pl;
}

// score = (1 + acos(clip(qk)))^(-5), masked -> (1+10000)^-5.
// acos via A&S 4.4.45 (|err| < ~7e-5 rad).
__device__ __forceinline__ float score_fn(float qk, float masked){
  float ax = fminf(fabsf(qk), 1.0f - 1e-7f);
  float t  = __builtin_amdgcn_sqrtf(1.0f - ax);
  float p  = __builtin_fmaf(__builtin_fmaf(__builtin_fmaf(-0.0187293f, ax, 0.0742610f),
                                           ax, -0.2121144f), ax, 1.5707288f);
  float t2 = t * p;
  float g  = (qk >= 0.0f) ? t2 : (3.14159265358979f - t2);
  g = (masked != 0.0f) ? 10000.0f : g;
  float w1 = 1.0f + g;
  float w2 = w1*w1;
  float w4 = w2*w2;
  float w5 = w4*w1;
  return __builtin_amdgcn_rcpf(w5);
}

// k1 (STORE=true): scores -> S bf16 (tile-blocked [bh][kt][row][64key]),
// col sums atomically into ncw. (STORE=false): fallback pass1, ncw=n_c^-0.5.
// Barrier-free main loop: K fragments in registers, Q fragments direct global.
template<bool STORE>
__global__ __launch_bounds__(256) void k1_score(
    const float* __restrict__ Q, const float* __restrict__ K,
    const int* __restrict__ mask, float* __restrict__ ncw,
    unsigned short* __restrict__ S)
{
  __shared__ float msk[64];
  __shared__ float red[64*4];

  const int kt = blockIdx.x, bh = blockIdx.y, rz = blockIdx.z;
  const int nz = gridDim.z;
  const int tid = threadIdx.x;
  const int wv = tid>>6, lane = tid&63, quad = lane>>4, l15 = lane&15;

  const float* Qg = Q + (size_t)bh*N_*D_;
  const float* Kg = K + (size_t)bh*N_*D_;

  short8 khi[4][2], klo[4][2];
  #pragma unroll
  for (int s=0;s<4;++s){
    const float* kp = Kg + (size_t)(kt*64 + s*16 + l15)*D_ + quad*8;
    load_split8(kp,      khi[s][0], klo[s][0]);
    load_split8(kp + 32, khi[s][1], klo[s][1]);
  }
  if (tid < 64)
    msk[tid] = (mask[(bh>>3)*N_ + kt*64 + tid] == 0) ? 1.f : 0.f;
  __syncthreads();

  float cs[4][4];
  #pragma unroll
  for (int s=0;s<4;++s)
    #pragma unroll
    for (int i=0;i<4;++i) cs[s][i] = 0.f;

  const int iters = NT_/nz;
  for (int rti=0; rti<iters; ++rti){
    const int rt = rz*iters + rti;
    const float* qp = Qg + (size_t)(rt*64 + wv*16 + l15)*D_ + quad*8;
    short8 bhi[2], blo[2];
    load_split8(qp,      bhi[0], blo[0]);
    load_split8(qp + 32, bhi[1], blo[1]);

    const size_t nrow = (size_t)(bh*NT_ + kt)*N_ + (size_t)rt*64 + wv*16 + l15;
    #pragma unroll
    for (int s=0;s<4;++s){
      float4v c = {0.f,0.f,0.f,0.f};
      #pragma unroll
      for (int cc=0; cc<2; ++cc){
        c = __builtin_amdgcn_mfma_f32_16x16x32_bf16(khi[s][cc], bhi[cc], c, 0,0,0);
        c = __builtin_amdgcn_mfma_f32_16x16x32_bf16(khi[s][cc], blo[cc], c, 0,0,0);
        c = __builtin_amdgcn_mfma_f32_16x16x32_bf16(klo[s][cc], bhi[cc], c, 0,0,0);
      }
      int kl = s*16 + quad*4;
      float sc0 = score_fn(c[0], msk[kl+0]);
      float sc1 = score_fn(c[1], msk[kl+1]);
      float sc2 = score_fn(c[2], msk[kl+2]);
      float sc3 = score_fn(c[3], msk[kl+3]);
      cs[s][0]+=sc0; cs[s][1]+=sc1; cs[s][2]+=sc2; cs[s][3]+=sc3;
      if (STORE){
        uint2 pk;
        pk.x = packbf2(sc0, sc1);
        pk.y = packbf2(sc2, sc3);
        *(uint2*)&S[nrow*64 + kl] = pk;
      }
    }
  }

  #pragma unroll
  for (int s=0;s<4;++s)
    #pragma unroll
    for (int i=0;i<4;++i){
      float v2 = cs[s][i];
      v2 += __shfl_xor(v2, 1);
      v2 += __shfl_xor(v2, 2);
      v2 += __shfl_xor(v2, 4);
      v2 += __shfl_xor(v2, 8);
      cs[s][i] = v2;
    }
  if (l15 == 0){
    #pragma unroll
    for (int s=0;s<4;++s)
      #pragma unroll
      for (int i=0;i<4;++i)
        red[(s*16 + quad*4 + i)*4 + wv] = cs[s][i];
  }
  __syncthreads();
  if (tid < 64){
    float t = red[tid*4+0] + red[tid*4+1] + red[tid*4+2] + red[tid*4+3];
    if (STORE) atomicAdd(&ncw[bh*N_ + kt*64 + tid], t);
    else       ncw[bh*N_ + kt*64 + tid] = 1.0f / sqrtf(t);
  }
}

// k2_pack: Vw in MFMA-fragment order: [bh][kt][f=0..9][lane][8 bf16]
//   f = s2*2+cc, s2<4: element j = w[key]*V[key][d], d=s2*16+l15,
//                       key = kt*64 + cc*32 + quad*8 + j
//   f = 8,9 (cc=f&1): l15==0 -> w[key], else 0   (rowsum operand row)
__global__ __launch_bounds__(256) void k2_pack(
    const float* __restrict__ V, const float* __restrict__ nc,
    unsigned short* __restrict__ Vw)
{
  __shared__ float T[64*65];    // T[d][m] = w*V^T for this tile
  __shared__ float wrow[64];
  const int mt = blockIdx.x, bh = blockIdx.y;
  const int tid = threadIdx.x;
  const float* Vg = V + (size_t)bh*N_*D_;
  const float* ncg = nc + (size_t)bh*N_;
  unsigned short* Fb = Vw + ((size_t)(bh*NT_ + mt)*10)*512;

  {
    int m = tid >> 2;
    int d0 = (tid & 3) * 16;
    int gm = mt*64 + m;
    float wm = 1.0f / sqrtf(fmaxf(ncg[gm], 1e-30f));
    if (d0 == 0) wrow[m] = wm;
    #pragma unroll
    for (int j=0;j<4;++j){
      float4v v = *(const float4v*)(Vg + (size_t)gm*D_ + d0 + j*4);
      T[(d0+j*4+0)*65 + m] = v.x*wm;
      T[(d0+j*4+1)*65 + m] = v.y*wm;
      T[(d0+j*4+2)*65 + m] = v.z*wm;
      T[(d0+j*4+3)*65 + m] = v.w*wm;
    }
  }
  __syncthreads();

  for (int idx = tid; idx < 640; idx += 256){
    int f = idx >> 6, lane = idx & 63;
    int quad = lane >> 4, l15 = lane & 15;
    int s2 = f >> 1, cc = f & 1;
    int m0 = cc*32 + quad*8;
    unsigned pk[4];
    if (s2 < 4){
      int d = s2*16 + l15;
      #pragma unroll
      for (int j=0;j<4;++j)
        pk[j] = packbf2(T[d*65 + m0 + 2*j], T[d*65 + m0 + 2*j + 1]);
    } else if (l15 == 0){
      #pragma unroll
      for (int j=0;j<4;++j)
        pk[j] = packbf2(wrow[m0 + 2*j], wrow[m0 + 2*j + 1]);
    } else {
      pk[0]=pk[1]=pk[2]=pk[3]=0u;
    }
    *(short8*)(Fb + ((size_t)f*64 + lane)*8) = *(short8*)pk;
  }
}

// k3_stream: out = (S diag(w) V) / (S w). 16 waves = 4 row-subtiles x 4
// k-chunks, zero barriers in main loop; fragment-contiguous Vw loads
// batched into va[10] before the MFMA chain; S prefetched 2 tiles ahead;
// LDS reduce across k-chunks at the end.  (Layouts identical to R10.)
__global__ __launch_bounds__(1024) void k3_stream(
    const unsigned short* __restrict__ S, const unsigned short* __restrict__ Vw,
    float* __restrict__ out)
{
  __shared__ float Red[4*3*16*68];   // 52224 B

  const int rt = blockIdx.x, bh = blockIdx.y;
  const int tid = threadIdx.x;
  const int wvid = tid >> 6;          // 0..15
  const int sr = wvid & 3;            // row subtile
  const int kc = wvid >> 2;           // k chunk (8 key tiles each)
  const int lane = tid & 63, quad = lane>>4, l15 = lane&15;

  float4v acc[4];
  #pragma unroll
  for (int i=0;i<4;++i) acc[i] = (float4v){0.f,0.f,0.f,0.f};
  float4v c5 = {0.f,0.f,0.f,0.f};

  // S row base for this wave's rows within a tile
  const size_t srow = (size_t)rt*64 + sr*16 + l15;

  // S double-buffer, 2 tiles ahead
  short8 npf0[2], npf1[2];
  #pragma unroll
  for (int d2=0; d2<2; ++d2){
    const size_t sb = ((size_t)(bh*NT_ + kc*8 + d2)*N_ + srow)*64;
    npf0[d2] = *(const short8*)&S[sb +  0 + quad*8];
    npf1[d2] = *(const short8*)&S[sb + 32 + quad*8];
  }

  for (int ki=0; ki<8; ++ki){
    const int kt = kc*8 + ki;
    const int cur = ki & 1;
    short8 pf0 = npf0[cur], pf1 = npf1[cur];
    if (ki < 6){
      const size_t sb = ((size_t)(bh*NT_ + kt + 2)*N_ + srow)*64;
      npf0[cur] = *(const short8*)&S[sb +  0 + quad*8];
      npf1[cur] = *(const short8*)&S[sb + 32 + quad*8];
    }
    // batch all 10 Vw fragment loads (dense lane*16) before the MFMA chain
    const unsigned short* F = Vw + ((size_t)(bh*NT_ + kt)*10)*512 + (size_t)lane*8;
    short8 va[10];
    #pragma unroll
    for (int f=0; f<10; ++f)
      va[f] = *(const short8*)(F + (size_t)f*512);

    #pragma unroll
    for (int s2=0;s2<4;++s2){
      acc[s2] = __builtin_amdgcn_mfma_f32_16x16x32_bf16(va[s2*2+0], pf0, acc[s2], 0,0,0);
      acc[s2] = __builtin_amdgcn_mfma_f32_16x16x32_bf16(va[s2*2+1], pf1, acc[s2], 0,0,0);
    }
    c5 = __builtin_amdgcn_mfma_f32_16x16x32_bf16(va[8], pf0, c5, 0,0,0);
    c5 = __builtin_amdgcn_mfma_f32_16x16x32_bf16(va[9], pf1, c5, 0,0,0);
  }

  if (kc > 0){
    float* Rr = Red + ((size_t)((sr*3 + (kc-1))*16) + l15)*68;
    #pragma unroll
    for (int s2=0;s2<4;++s2)
      #pragma unroll
      for (int i=0;i<4;++i)
        Rr[s2*16 + quad*4 + i] = acc[s2][i];
    if (quad == 0) Rr[64] = c5[0];
  }
  __syncthreads();
  if (kc == 0){
    #pragma unroll
    for (int p=0; p<3; ++p){
      const float* Rr = Red + ((size_t)((sr*3 + p)*16) + l15)*68;
      #pragma unroll
      for (int s2=0;s2<4;++s2)
        #pragma unroll
        for (int i=0;i<4;++i)
          acc[s2][i] += Rr[s2*16 + quad*4 + i];
    }
    float rs = __shfl(c5[0], l15);
    #pragma unroll
    for (int p=0; p<3; ++p)
      rs += Red[((size_t)((sr*3 + p)*16) + l15)*68 + 64];
    float inv = 1.0f / fmaxf(rs, 1e-12f);

    float* Og = out + (size_t)bh*N_*D_ + (size_t)(rt*64 + sr*16 + l15)*D_;
    #pragma unroll
    for (int s2=0;s2<4;++s2)
      #pragma unroll
      for (int i=0;i<4;++i)
        Og[s2*16 + quad*4 + i] = acc[s2][i] * inv;
  }
}

// fallback pass2 (round-3 structure, verified)
__global__ __launch_bounds__(256) void spop_pass2(
    const float* __restrict__ Q, const float* __restrict__ K,
    const float* __restrict__ V, const int* __restrict__ mask,
    const float* __restrict__ w, float* __restrict__ out)
{
  __shared__ unsigned short Khi[64*LS], Klo[64*LS];
  __shared__ unsigned short Vt[64*LS];
  __shared__ unsigned short Ps[64*LS];
  __shared__ float msk[64], wms[64];

  const int rt = blockIdx.x, bh = blockIdx.y, b = bh>>3;
  const int tid = threadIdx.x;
  const int wv = tid>>6, lane = tid&63, quad = lane>>4, l15 = lane&15;

  const float* Qg = Q + (size_t)bh*N_*D_;
  const float* Kg = K + (size_t)bh*N_*D_;
  const float* Vg = V + (size_t)bh*N_*D_;

  short8 qhi[2], qlo[2];
  {
    const float* qp = Qg + (size_t)(rt*64 + wv*16 + l15)*D_ + quad*8;
    load_split8(qp,      qhi[0], qlo[0]);
    load_split8(qp + 32, qhi[1], qlo[1]);
  }

  float4v acc[4];
  #pragma unroll
  for (int i=0;i<4;++i) acc[i] = (float4v){0.f,0.f,0.f,0.f};
  float rs = 0.f;

  for (int kt=0; kt<NT_; ++kt){
    __syncthreads();
    #pragma unroll
    for (int it=0; it<4; ++it){
      int idx = tid + it*256;
      int r = idx>>4, d4 = (idx&15)<<2;
      const float4v v = *(const float4v*)(Kg + (size_t)(kt*64 + r)*D_ + d4);
      unsigned h0,l0,h1,l1;
      split2(v.x, v.y, h0, l0);
      split2(v.z, v.w, h1, l1);
      unsigned* KhiW = (unsigned*)Khi; unsigned* KloW = (unsigned*)Klo;
      int base = r*LSW + (d4>>1);
      KhiW[base] = h0; KhiW[base+1] = h1;
      KloW[base] = l0; KloW[base+1] = l1;
    }
    #pragma unroll
    for (int it=0; it<2; ++it){
      int u = tid + it*256;
      int kp = u & 31;
      int d4 = (u>>5)<<2;
      const float* vp = Vg + (size_t)(kt*64 + kp*2)*D_ + d4;
      float4v a0 = *(const float4v*)vp;
      float4v a1 = *(const float4v*)(vp + D_);
      unsigned* VtW = (unsigned*)Vt;
      VtW[(d4+0)*LSW + kp] = packbf2(a0.x, a1.x);
      VtW[(d4+1)*LSW + kp] = packbf2(a0.y, a1.y);
      VtW[(d4+2)*LSW + kp] = packbf2(a0.z, a1.z);
      VtW[(d4+3)*LSW + kp] = packbf2(a0.w, a1.w);
    }
    if (tid < 64){
      int gk = kt*64 + tid;
      msk[tid] = (mask[b*N_ + gk] == 0) ? 1.f : 0.f;
      wms[tid] = w[bh*N_ + gk];
    }
    __syncthreads();

    #pragma unroll
    for (int s=0;s<4;++s){
      float4v c = {0.f,0.f,0.f,0.f};
      #pragma unroll
      for (int cc=0; cc<2; ++cc){
        const short8 ahi = *(const short8*)&Khi[(s*16+l15)*LS + cc*32 + quad*8];
        const short8 alo = *(const short8*)&Klo[(s*16+l15)*LS + cc*32 + quad*8];
        c = __builtin_amdgcn_mfma_f32_16x16x32_bf16(ahi, qhi[cc], c, 0,0,0);
        c = __builtin_amdgcn_mfma_f32_16x16x32_bf16(ahi, qlo[cc], c, 0,0,0);
        c = __builtin_amdgcn_mfma_f32_16x16x32_bf16(alo, qhi[cc], c, 0,0,0);
      }
      int kl = s*16 + quad*4;
      float sc0 = score_fn(c[0], msk[kl+0]) * wms[kl+0];
      float sc1 = score_fn(c[1], msk[kl+1]) * wms[kl+1];
      float sc2 = score_fn(c[2], msk[kl+2]) * wms[kl+2];
      float sc3 = score_fn(c[3], msk[kl+3]) * wms[kl+3];
      rs += (sc0 + sc1) + (sc2 + sc3);
      unsigned* PsW = (unsigned*)Ps;
      int pb = (wv*16 + l15)*LSW + (kl>>1);
      PsW[pb]   = packbf2(sc0, sc1);
      PsW[pb+1] = packbf2(sc2, sc3);
    }

    short8 pf[2];
    pf[0] = *(const short8*)&Ps[(wv*16+l15)*LS +  0 + quad*8];
    pf[1] = *(const short8*)&Ps[(wv*16+l15)*LS + 32 + quad*8];
    #pragma unroll
    for (int s2=0;s2<4;++s2){
      #pragma unroll
      for (int cc=0; cc<2; ++cc){
        const short8 av = *(const short8*)&Vt[(s2*16+l15)*LS + cc*32 + quad*8];
        acc[s2] = __builtin_amdgcn_mfma_f32_16x16x32_bf16(av, pf[cc], acc[s2], 0,0,0);
      }
    }
  }

  rs += __shfl_xor(rs, 16);
  rs += __shfl_xor(rs, 32);
  float inv = 1.0f / fmaxf(rs, 1e-12f);

  float* Og = out + (size_t)bh*N_*D_ + (size_t)(rt*64 + wv*16 + l15)*D_;
  #pragma unroll
  for (int s2=0;s2<4;++s2)
    #pragma unroll
    for (int i=0;i<4;++i)
      Og[s2*16 + quad*4 + i] = acc[s2][i] * inv;
}

extern "C" void kernel_launch(void* const* d_in, const int* in_sizes, int n_in,
                              void* d_out, int out_size, void* d_ws, size_t ws_size,
                              hipStream_t stream) {
  (void)in_sizes; (void)n_in; (void)out_size;
  const float* Q   = (const float*)d_in[0];
  const float* K   = (const float*)d_in[1];
  const float* V   = (const float*)d_in[2];
  const int*  mask = (const int*)d_in[3];
  float* out = (float*)d_out;

  const size_t nc_bytes = (size_t)BH_*N_*sizeof(float);        // 128 KB
  const size_t vw_off   = 131072;
  const size_t vw_bytes = (size_t)BH_*NT_*10*512*2;            // 5.24 MB
  const size_t s_off    = vw_off + vw_bytes;
  const size_t S_bytes  = (size_t)2*BH_*N_*N_;                 // 128 MiB
  const size_t need     = s_off + S_bytes;                     // ~139.6 MB (proven fits)

  if (ws_size >= need){
    float* nc = (float*)d_ws;
    unsigned short* Vw = (unsigned short*)((char*)d_ws + vw_off);
    unsigned short* S  = (unsigned short*)((char*)d_ws + s_off);
    hipMemsetAsync(nc, 0, nc_bytes, stream);
    k1_score<true><<<dim3(NT_, BH_, 4), 256, 0, stream>>>(Q, K, mask, nc, S);
    k2_pack<<<dim3(NT_, BH_), 256, 0, stream>>>(V, nc, Vw);
    k3_stream<<<dim3(NT_, BH_), 1024, 0, stream>>>(S, Vw, out);
  } else {
    float* w = (float*)d_ws;
    k1_score<false><<<dim3(NT_, BH_, 1), 256, 0, stream>>>(Q, K, mask, w, nullptr);
    spop_pass2<<<dim3(NT_, BH_), 256, 0, stream>>>(Q, K, V, mask, w, out);
  }
}

// Round 14
// 188.868 us; speedup vs baseline: 1.3952x; 1.0242x over previous
//
#include <hip/hip_runtime.h>
#include <hip/hip_bf16.h>
#include <math.h>

#define B_ 2
#define H_ 8
#define N_ 2048
#define D_ 64
#define BH_ 16
#define NT_ (N_/64)
#define LS 72
#define LSW (LS/2)

typedef __attribute__((ext_vector_type(8))) short short8;
typedef __attribute__((ext_vector_type(4))) float float4v;

__device__ __forceinline__ unsigned packbf2(float a, float b){
  __hip_bfloat162 h = __float22bfloat162_rn(make_float2(a, b));
  return *(unsigned*)&h;
}
__device__ __forceinline__ void split2(float a, float b, unsigned& hi, unsigned& lo){
  hi = packbf2(a, b);
  float ha = __uint_as_float(hi << 16);
  float hb = __uint_as_float(hi & 0xFFFF0000u);
  lo = packbf2(a - ha, b - hb);
}
__device__ __forceinline__ void load_split8(const float* p, short8& hi8, short8& lo8){
  float4v v0 = *(const float4v*)p;
  float4v v1 = *(const float4v*)(p + 4);
  unsigned h0,h1,h2,h3,l0,l1,l2,l3;
  split2(v0.x, v0.y, h0, l0);
  split2(v0.z, v0.w, h1, l1);
  split2(v1.x, v1.y, h2, l2);
  split2(v1.z, v1.w, h3, l3);
  unsigned ph[4] = {h0,h1,h2,h3};
  unsigned pl[4] = {l0,l1,l2,l3};
  hi8 = *(short8*)ph;
  lo8 = *(short8*)pl;
}

// score = (1 + acos(clip(qk)))^(-5), masked -> (1+10000)^-5.
// acos via A&S 4.4.45 (|err| < ~7e-5 rad).
__device__ __forceinline__ float score_fn(float qk, float masked){
  float ax = fminf(fabsf(qk), 1.0f - 1e-7f);
  float t  = __builtin_amdgcn_sqrtf(1.0f - ax);
  float p  = __builtin_fmaf(__builtin_fmaf(__builtin_fmaf(-0.0187293f, ax, 0.0742610f),
                                           ax, -0.2121144f), ax, 1.5707288f);
  float t2 = t * p;
  float g  = (qk >= 0.0f) ? t2 : (3.14159265358979f - t2);
  g = (masked != 0.0f) ? 10000.0f : g;
  float w1 = 1.0f + g;
  float w2 = w1*w1;
  float w4 = w2*w2;
  float w5 = w4*w1;
  return __builtin_amdgcn_rcpf(w5);
}

// k1 (STORE=true): scores -> S bf16 (tile-blocked [bh][kt][row][64key]),
// col sums atomically into ncw. (STORE=false): fallback pass1, ncw=n_c^-0.5.
// Barrier-free main loop: K fragments in registers, Q fragments direct global.
template<bool STORE>
__global__ __launch_bounds__(256) void k1_score(
    const float* __restrict__ Q, const float* __restrict__ K,
    const int* __restrict__ mask, float* __restrict__ ncw,
    unsigned short* __restrict__ S)
{
  __shared__ float msk[64];
  __shared__ float red[64*4];

  const int kt = blockIdx.x, bh = blockIdx.y, rz = blockIdx.z;
  const int nz = gridDim.z;
  const int tid = threadIdx.x;
  const int wv = tid>>6, lane = tid&63, quad = lane>>4, l15 = lane&15;

  const float* Qg = Q + (size_t)bh*N_*D_;
  const float* Kg = K + (size_t)bh*N_*D_;

  short8 khi[4][2], klo[4][2];
  #pragma unroll
  for (int s=0;s<4;++s){
    const float* kp = Kg + (size_t)(kt*64 + s*16 + l15)*D_ + quad*8;
    load_split8(kp,      khi[s][0], klo[s][0]);
    load_split8(kp + 32, khi[s][1], klo[s][1]);
  }
  if (tid < 64)
    msk[tid] = (mask[(bh>>3)*N_ + kt*64 + tid] == 0) ? 1.f : 0.f;
  __syncthreads();

  float cs[4][4];
  #pragma unroll
  for (int s=0;s<4;++s)
    #pragma unroll
    for (int i=0;i<4;++i) cs[s][i] = 0.f;

  const int iters = NT_/nz;
  for (int rti=0; rti<iters; ++rti){
    const int rt = rz*iters + rti;
    const float* qp = Qg + (size_t)(rt*64 + wv*16 + l15)*D_ + quad*8;
    short8 bhi[2], blo[2];
    load_split8(qp,      bhi[0], blo[0]);
    load_split8(qp + 32, bhi[1], blo[1]);

    const size_t nrow = (size_t)(bh*NT_ + kt)*N_ + (size_t)rt*64 + wv*16 + l15;
    #pragma unroll
    for (int s=0;s<4;++s){
      float4v c = {0.f,0.f,0.f,0.f};
      #pragma unroll
      for (int cc=0; cc<2; ++cc){
        c = __builtin_amdgcn_mfma_f32_16x16x32_bf16(khi[s][cc], bhi[cc], c, 0,0,0);
        c = __builtin_amdgcn_mfma_f32_16x16x32_bf16(khi[s][cc], blo[cc], c, 0,0,0);
        c = __builtin_amdgcn_mfma_f32_16x16x32_bf16(klo[s][cc], bhi[cc], c, 0,0,0);
      }
      int kl = s*16 + quad*4;
      float sc0 = score_fn(c[0], msk[kl+0]);
      float sc1 = score_fn(c[1], msk[kl+1]);
      float sc2 = score_fn(c[2], msk[kl+2]);
      float sc3 = score_fn(c[3], msk[kl+3]);
      cs[s][0]+=sc0; cs[s][1]+=sc1; cs[s][2]+=sc2; cs[s][3]+=sc3;
      if (STORE){
        uint2 pk;
        pk.x = packbf2(sc0, sc1);
        pk.y = packbf2(sc2, sc3);
        *(uint2*)&S[nrow*64 + kl] = pk;
      }
    }
  }

  #pragma unroll
  for (int s=0;s<4;++s)
    #pragma unroll
    for (int i=0;i<4;++i){
      float v2 = cs[s][i];
      v2 += __shfl_xor(v2, 1);
      v2 += __shfl_xor(v2, 2);
      v2 += __shfl_xor(v2, 4);
      v2 += __shfl_xor(v2, 8);
      cs[s][i] = v2;
    }
  if (l15 == 0){
    #pragma unroll
    for (int s=0;s<4;++s)
      #pragma unroll
      for (int i=0;i<4;++i)
        red[(s*16 + quad*4 + i)*4 + wv] = cs[s][i];
  }
  __syncthreads();
  if (tid < 64){
    float t = red[tid*4+0] + red[tid*4+1] + red[tid*4+2] + red[tid*4+3];
    if (STORE) atomicAdd(&ncw[bh*N_ + kt*64 + tid], t);
    else       ncw[bh*N_ + kt*64 + tid] = 1.0f / sqrtf(t);
  }
}

// k2_pack: Vw in MFMA-fragment order: [bh][kt][f=0..9][lane][8 bf16]
//   f = s2*2+cc, s2<4: element j = w[key]*V[key][d], d=s2*16+l15,
//                       key = kt*64 + cc*32 + quad*8 + j
//   f = 8,9 (cc=f&1): l15==0 -> w[key], else 0   (rowsum operand row)
__global__ __launch_bounds__(256) void k2_pack(
    const float* __restrict__ V, const float* __restrict__ nc,
    unsigned short* __restrict__ Vw)
{
  __shared__ float T[64*65];    // T[d][m] = w*V^T for this tile
  __shared__ float wrow[64];
  const int mt = blockIdx.x, bh = blockIdx.y;
  const int tid = threadIdx.x;
  const float* Vg = V + (size_t)bh*N_*D_;
  const float* ncg = nc + (size_t)bh*N_;
  unsigned short* Fb = Vw + ((size_t)(bh*NT_ + mt)*10)*512;

  {
    int m = tid >> 2;
    int d0 = (tid & 3) * 16;
    int gm = mt*64 + m;
    float wm = 1.0f / sqrtf(fmaxf(ncg[gm], 1e-30f));
    if (d0 == 0) wrow[m] = wm;
    #pragma unroll
    for (int j=0;j<4;++j){
      float4v v = *(const float4v*)(Vg + (size_t)gm*D_ + d0 + j*4);
      T[(d0+j*4+0)*65 + m] = v.x*wm;
      T[(d0+j*4+1)*65 + m] = v.y*wm;
      T[(d0+j*4+2)*65 + m] = v.z*wm;
      T[(d0+j*4+3)*65 + m] = v.w*wm;
    }
  }
  __syncthreads();

  for (int idx = tid; idx < 640; idx += 256){
    int f = idx >> 6, lane = idx & 63;
    int quad = lane >> 4, l15 = lane & 15;
    int s2 = f >> 1, cc = f & 1;
    int m0 = cc*32 + quad*8;
    unsigned pk[4];
    if (s2 < 4){
      int d = s2*16 + l15;
      #pragma unroll
      for (int j=0;j<4;++j)
        pk[j] = packbf2(T[d*65 + m0 + 2*j], T[d*65 + m0 + 2*j + 1]);
    } else if (l15 == 0){
      #pragma unroll
      for (int j=0;j<4;++j)
        pk[j] = packbf2(wrow[m0 + 2*j], wrow[m0 + 2*j + 1]);
    } else {
      pk[0]=pk[1]=pk[2]=pk[3]=0u;
    }
    *(short8*)(Fb + ((size_t)f*64 + lane)*8) = *(short8*)pk;
  }
}

// k3_lds: out = (S diag(w) V) / (S w). Grid 16x16 (1 block/CU), 1024 threads
// = 16 waves = 8 row-slots (128 rows) x 2 kt-halves. The two active Vw tiles
// (20 KB) are double-buffer staged in LDS once per block -> Vw global traffic
// drops 8x. S streamed from global with next-iter register prefetch.
// Final cross-half reduce reuses the staging LDS after the last barrier.
__global__ __launch_bounds__(1024) void k3_lds(
    const unsigned short* __restrict__ S, const unsigned short* __restrict__ Vw,
    float* __restrict__ out)
{
  __shared__ unsigned short Vs[2*2*10*512];   // 40960 B; overlaid by Red (34816 B)

  const int rtp = blockIdx.x, bh = blockIdx.y;
  const int tid = threadIdx.x;
  const int wvid = tid >> 6;
  const int g    = wvid >> 3;          // kt half: 0 -> kt 0..15, 1 -> 16..31
  const int slot = wvid & 7;           // row slot: rows rtp*128 + slot*16 + l15
  const int lane = tid & 63, quad = lane >> 4, l15 = lane & 15;

  const int row = rtp*128 + slot*16 + l15;

  float4v acc[4];
  #pragma unroll
  for (int i=0;i<4;++i) acc[i] = (float4v){0.f,0.f,0.f,0.f};
  float4v c5 = {0.f,0.f,0.f,0.f};

  // stage it=0 into buf 0 (both kt halves)
  for (int c = tid; c < 1280; c += 1024){
    const int gg = (c >= 640) ? 1 : 0;
    const int rem = c - gg*640;
    const int f = rem >> 6, ln = rem & 63;
    const int kt = gg*16;              // it = 0
    *(short8*)&Vs[(((0*2 + gg)*10 + f) << 9) + ln*8] =
      *(const short8*)&Vw[(((size_t)(bh*NT_ + kt)*10 + f) << 9) + ln*8];
  }
  // prefetch S for it=0
  short8 npf0, npf1;
  {
    const size_t sb = ((size_t)(bh*NT_ + g*16)*N_ + row)*64;
    npf0 = *(const short8*)&S[sb + quad*8];
    npf1 = *(const short8*)&S[sb + 32 + quad*8];
  }
  __syncthreads();

  for (int it = 0; it < 16; ++it){
    const int cur = it & 1, nxt = cur ^ 1;
    short8 pf0 = npf0, pf1 = npf1;
    if (it < 15){
      // prefetch next-iter S
      const size_t sb = ((size_t)(bh*NT_ + g*16 + it + 1)*N_ + row)*64;
      npf0 = *(const short8*)&S[sb + quad*8];
      npf1 = *(const short8*)&S[sb + 32 + quad*8];
      // stage next-iter Vw tiles into the other buffer
      for (int c = tid; c < 1280; c += 1024){
        const int gg = (c >= 640) ? 1 : 0;
        const int rem = c - gg*640;
        const int f = rem >> 6, ln = rem & 63;
        const int kt2 = gg*16 + it + 1;
        *(short8*)&Vs[(((nxt*2 + gg)*10 + f) << 9) + ln*8] =
          *(const short8*)&Vw[(((size_t)(bh*NT_ + kt2)*10 + f) << 9) + ln*8];
      }
    }
    const unsigned short* Fl = &Vs[((cur*2 + g)*10) << 9] + (size_t)lane*8;
    short8 va[10];
    #pragma unroll
    for (int f=0; f<10; ++f)
      va[f] = *(const short8*)(Fl + ((size_t)f << 9));

    #pragma unroll
    for (int s2=0;s2<4;++s2){
      acc[s2] = __builtin_amdgcn_mfma_f32_16x16x32_bf16(va[s2*2+0], pf0, acc[s2], 0,0,0);
      acc[s2] = __builtin_amdgcn_mfma_f32_16x16x32_bf16(va[s2*2+1], pf1, acc[s2], 0,0,0);
    }
    c5 = __builtin_amdgcn_mfma_f32_16x16x32_bf16(va[8], pf0, c5, 0,0,0);
    c5 = __builtin_amdgcn_mfma_f32_16x16x32_bf16(va[9], pf1, c5, 0,0,0);

    __syncthreads();   // cur reads done + nxt writes done
  }

  // reduce across the two kt halves (Red overlays Vs; safe after last barrier)
  float* Red = (float*)Vs;
  if (g == 1){
    float* Rr = Red + (size_t)(slot*16 + l15)*68;
    #pragma unroll
    for (int s2=0;s2<4;++s2)
      #pragma unroll
      for (int i=0;i<4;++i)
        Rr[s2*16 + quad*4 + i] = acc[s2][i];
    if (quad == 0) Rr[64] = c5[0];
  }
  __syncthreads();
  if (g == 0){
    const float* Rr = Red + (size_t)(slot*16 + l15)*68;
    #pragma unroll
    for (int s2=0;s2<4;++s2)
      #pragma unroll
      for (int i=0;i<4;++i)
        acc[s2][i] += Rr[s2*16 + quad*4 + i];
    float rs = __shfl(c5[0], l15) + Rr[64];
    float inv = 1.0f / fmaxf(rs, 1e-12f);

    float* Og = out + (size_t)bh*N_*D_ + (size_t)row*D_;
    #pragma unroll
    for (int s2=0;s2<4;++s2)
      #pragma unroll
      for (int i=0;i<4;++i)
        Og[s2*16 + quad*4 + i] = acc[s2][i] * inv;
  }
}

// fallback pass2 (round-3 structure, verified)
__global__ __launch_bounds__(256) void spop_pass2(
    const float* __restrict__ Q, const float* __restrict__ K,
    const float* __restrict__ V, const int* __restrict__ mask,
    const float* __restrict__ w, float* __restrict__ out)
{
  __shared__ unsigned short Khi[64*LS], Klo[64*LS];
  __shared__ unsigned short Vt[64*LS];
  __shared__ unsigned short Ps[64*LS];
  __shared__ float msk[64], wms[64];

  const int rt = blockIdx.x, bh = blockIdx.y, b = bh>>3;
  const int tid = threadIdx.x;
  const int wv = tid>>6, lane = tid&63, quad = lane>>4, l15 = lane&15;

  const float* Qg = Q + (size_t)bh*N_*D_;
  const float* Kg = K + (size_t)bh*N_*D_;
  const float* Vg = V + (size_t)bh*N_*D_;

  short8 qhi[2], qlo[2];
  {
    const float* qp = Qg + (size_t)(rt*64 + wv*16 + l15)*D_ + quad*8;
    load_split8(qp,      qhi[0], qlo[0]);
    load_split8(qp + 32, qhi[1], qlo[1]);
  }

  float4v acc[4];
  #pragma unroll
  for (int i=0;i<4;++i) acc[i] = (float4v){0.f,0.f,0.f,0.f};
  float rs = 0.f;

  for (int kt=0; kt<NT_; ++kt){
    __syncthreads();
    #pragma unroll
    for (int it=0; it<4; ++it){
      int idx = tid + it*256;
      int r = idx>>4, d4 = (idx&15)<<2;
      const float4v v = *(const float4v*)(Kg + (size_t)(kt*64 + r)*D_ + d4);
      unsigned h0,l0,h1,l1;
      split2(v.x, v.y, h0, l0);
      split2(v.z, v.w, h1, l1);
      unsigned* KhiW = (unsigned*)Khi; unsigned* KloW = (unsigned*)Klo;
      int base = r*LSW + (d4>>1);
      KhiW[base] = h0; KhiW[base+1] = h1;
      KloW[base] = l0; KloW[base+1] = l1;
    }
    #pragma unroll
    for (int it=0; it<2; ++it){
      int u = tid + it*256;
      int kp = u & 31;
      int d4 = (u>>5)<<2;
      const float* vp = Vg + (size_t)(kt*64 + kp*2)*D_ + d4;
      float4v a0 = *(const float4v*)vp;
      float4v a1 = *(const float4v*)(vp + D_);
      unsigned* VtW = (unsigned*)Vt;
      VtW[(d4+0)*LSW + kp] = packbf2(a0.x, a1.x);
      VtW[(d4+1)*LSW + kp] = packbf2(a0.y, a1.y);
      VtW[(d4+2)*LSW + kp] = packbf2(a0.z, a1.z);
      VtW[(d4+3)*LSW + kp] = packbf2(a0.w, a1.w);
    }
    if (tid < 64){
      int gk = kt*64 + tid;
      msk[tid] = (mask[b*N_ + gk] == 0) ? 1.f : 0.f;
      wms[tid] = w[bh*N_ + gk];
    }
    __syncthreads();

    #pragma unroll
    for (int s=0;s<4;++s){
      float4v c = {0.f,0.f,0.f,0.f};
      #pragma unroll
      for (int cc=0; cc<2; ++cc){
        const short8 ahi = *(const short8*)&Khi[(s*16+l15)*LS + cc*32 + quad*8];
        const short8 alo = *(const short8*)&Klo[(s*16+l15)*LS + cc*32 + quad*8];
        c = __builtin_amdgcn_mfma_f32_16x16x32_bf16(ahi, qhi[cc], c, 0,0,0);
        c = __builtin_amdgcn_mfma_f32_16x16x32_bf16(ahi, qlo[cc], c, 0,0,0);
        c = __builtin_amdgcn_mfma_f32_16x16x32_bf16(alo, qhi[cc], c, 0,0,0);
      }
      int kl = s*16 + quad*4;
      float sc0 = score_fn(c[0], msk[kl+0]) * wms[kl+0];
      float sc1 = score_fn(c[1], msk[kl+1]) * wms[kl+1];
      float sc2 = score_fn(c[2], msk[kl+2]) * wms[kl+2];
      float sc3 = score_fn(c[3], msk[kl+3]) * wms[kl+3];
      rs += (sc0 + sc1) + (sc2 + sc3);
      unsigned* PsW = (unsigned*)Ps;
      int pb = (wv*16 + l15)*LSW + (kl>>1);
      PsW[pb]   = packbf2(sc0, sc1);
      PsW[pb+1] = packbf2(sc2, sc3);
    }

    short8 pf[2];
    pf[0] = *(const short8*)&Ps[(wv*16+l15)*LS +  0 + quad*8];
    pf[1] = *(const short8*)&Ps[(wv*16+l15)*LS + 32 + quad*8];
    #pragma unroll
    for (int s2=0;s2<4;++s2){
      #pragma unroll
      for (int cc=0; cc<2; ++cc){
        const short8 av = *(const short8*)&Vt[(s2*16+l15)*LS + cc*32 + quad*8];
        acc[s2] = __builtin_amdgcn_mfma_f32_16x16x32_bf16(av, pf[cc], acc[s2], 0,0,0);
      }
    }
  }

  rs += __shfl_xor(rs, 16);
  rs += __shfl_xor(rs, 32);
  float inv = 1.0f / fmaxf(rs, 1e-12f);

  float* Og = out + (size_t)bh*N_*D_ + (size_t)(rt*64 + wv*16 + l15)*D_;
  #pragma unroll
  for (int s2=0;s2<4;++s2)
    #pragma unroll
    for (int i=0;i<4;++i)
      Og[s2*16 + quad*4 + i] = acc[s2][i] * inv;
}

extern "C" void kernel_launch(void* const* d_in, const int* in_sizes, int n_in,
                              void* d_out, int out_size, void* d_ws, size_t ws_size,
                              hipStream_t stream) {
  (void)in_sizes; (void)n_in; (void)out_size;
  const float* Q   = (const float*)d_in[0];
  const float* K   = (const float*)d_in[1];
  const float* V   = (const float*)d_in[2];
  const int*  mask = (const int*)d_in[3];
  float* out = (float*)d_out;

  const size_t nc_bytes = (size_t)BH_*N_*sizeof(float);        // 128 KB
  const size_t vw_off   = 131072;
  const size_t vw_bytes = (size_t)BH_*NT_*10*512*2;            // 5.24 MB
  const size_t s_off    = vw_off + vw_bytes;
  const size_t S_bytes  = (size_t)2*BH_*N_*N_;                 // 128 MiB
  const size_t need     = s_off + S_bytes;                     // ~139.6 MB (proven fits)

  if (ws_size >= need){
    float* nc = (float*)d_ws;
    unsigned short* Vw = (unsigned short*)((char*)d_ws + vw_off);
    unsigned short* S  = (unsigned short*)((char*)d_ws + s_off);
    hipMemsetAsync(nc, 0, nc_bytes, stream);
    k1_score<true><<<dim3(NT_, BH_, 4), 256, 0, stream>>>(Q, K, mask, nc, S);
    k2_pack<<<dim3(NT_, BH_), 256, 0, stream>>>(V, nc, Vw);
    k3_lds<<<dim3(N_/128, BH_), 1024, 0, stream>>>(S, Vw, out);
  } else {
    float* w = (float*)d_ws;
    k1_score<false><<<dim3(NT_, BH_, 1), 256, 0, stream>>>(Q, K, mask, w, nullptr);
    spop_pass2<<<dim3(NT_, BH_), 256, 0, stream>>>(Q, K, V, mask, w, out);
  }
}